// Round 7
// baseline (74.162 us; speedup 1.0000x reference)
//
#include <hip/hip_runtime.h>
#include <math.h>

// Cox partial likelihood NLL.
// loss = -(1/n) * sum_i e_i * (risk_i - log(P[time_i]))
//   where P[t] = sum_{t' <= t} S[t'],  S[t] = sum_{time_j = t} exp(risk_j)
// Decompose: A = sum_i e_i*risk_i ; B = sum_t E[t]*log(P[t]), E[t] = sum_{time_j=t} e_j
// loss = -(A - B)/n
//
// R7: ZERO atomics in the hot path. Each wave owns a contiguous 1024-elem
// strip; runs closing inside the strip are that bucket's SOLE contribution
// (sorted times) -> plain stores. Only the strip's first/last runs can cross
// strip boundaries -> per-strip side slots, combined by a tiny fix-up kernel.
// R1-R6 evidence: ~5000-cyc wave stalls from device-scope atomics queueing on
// hot S/E lines (shared vmcnt drain); everything else was second-order.

#define TMAXV   100000
#define NPAD    100352          // 98 * 1024, padded bucket count
#define NBLK_SC 98
#define VPT     16              // elements per thread per window
#define NWIN    2               // windows per block
#define NBLK1   2048            // k1 grid: 2048 * 2 * 4096 = 16,777,216
#define NS      (NBLK1 * NWIN * 4)   // strips = blocks x windows x 4 waves = 16384
#define SENT    0x7fffffff      // sentinel time (never flushed)

__device__ __forceinline__ void atomAddF(float* p, float v) {
    unsafeAtomicAdd(p, v);      // native global_atomic_add_f32 (fix-up only)
}

// Block reduce (up to 16 waves). Result valid in lane 0 of wave 0 only.
__device__ __forceinline__ float block_reduce_sum(float v, float* lds) {
    const int lane = threadIdx.x & 63;
    const int wid  = threadIdx.x >> 6;
    #pragma unroll
    for (int d = 32; d > 0; d >>= 1) v += __shfl_down(v, d);
    __syncthreads();
    if (lane == 0) lds[wid] = v;
    __syncthreads();
    float r = 0.f;
    if (wid == 0) {
        const int nw = (int)(blockDim.x >> 6);
        r = (lane < nw) ? lds[lane] : 0.f;
        #pragma unroll
        for (int d = 8; d > 0; d >>= 1) r += __shfl_down(r, d);
    }
    return r;
}

__global__ __launch_bounds__(256)
void k1_bucket(const float* __restrict__ risk, const float* __restrict__ ev,
               const int* __restrict__ tim,
               float* __restrict__ S, float* __restrict__ E,
               float* __restrict__ Apart,
               int* __restrict__ tF, float* __restrict__ vF, float* __restrict__ wF,
               int* __restrict__ tL, float* __restrict__ vL, float* __restrict__ wL,
               int n) {
    __shared__ float lds[16];
    const int tid   = (int)threadIdx.x;
    const int lane  = tid & 63;
    const int start = (int)blockIdx.x * (NWIN * 256 * VPT);
    int end_blk = start + NWIN * 256 * VPT;
    if (end_blk > n) end_blk = n;

    float accA = 0.f;

    #pragma unroll
    for (int win = 0; win < NWIN; ++win) {
        const int base = start + win * (256 * VPT) + tid * VPT;
        const int sid  = (((int)blockIdx.x * NWIN + win) << 2) | (tid >> 6);

        float r[VPT], w[VPT];
        int   t[VPT];
        if (base + VPT <= end_blk) {
            #pragma unroll
            for (int q = 0; q < VPT / 4; ++q) {
                const float4 rr = *(const float4*)(risk + base + 4 * q);
                const float4 ww = *(const float4*)(ev   + base + 4 * q);
                const int4   tt = *(const int4*)(tim   + base + 4 * q);
                r[4*q+0]=rr.x; r[4*q+1]=rr.y; r[4*q+2]=rr.z; r[4*q+3]=rr.w;
                w[4*q+0]=ww.x; w[4*q+1]=ww.y; w[4*q+2]=ww.z; w[4*q+3]=ww.w;
                t[4*q+0]=tt.x; t[4*q+1]=tt.y; t[4*q+2]=tt.z; t[4*q+3]=tt.w;
            }
        } else {
            #pragma unroll
            for (int j = 0; j < VPT; ++j) {
                const int i = base + j;
                const bool ok = (i < end_blk);
                r[j] = ok ? risk[i] : 0.f;
                w[j] = ok ? ev[i]   : 0.f;
                t[j] = ok ? tim[i]  : SENT;
            }
        }

        float ve[VPT];
        #pragma unroll
        for (int j = 0; j < VPT; ++j) {
            ve[j] = __expf(r[j]);
            accA += w[j] * r[j];          // w==0 for invalid lanes
        }

        const int head_t = t[0];
        const int tail_t = t[VPT - 1];
        const int sfirst = __shfl(head_t, 0);    // strip = this wave's 1024 elems
        const int slast  = __shfl(tail_t, 63);

        // trailing-run sums (times sorted => equality to tail is contiguous)
        float tsv = 0.f, tsw = 0.f;
        #pragma unroll
        for (int j = 0; j < VPT; ++j) {
            if (t[j] == tail_t) { tsv += ve[j]; tsw += w[j]; }
        }

        // cross-lane segmented inclusive scan of trailing sums, keyed on tail_t
        float Sv = tsv, Sw = tsw;
        #pragma unroll
        for (int d = 1; d < 64; d <<= 1) {
            const float ov = __shfl_up(Sv, d);
            const float ow = __shfl_up(Sw, d);
            const int   ok = __shfl_up(tail_t, d);
            if (lane >= d && ok == tail_t) { Sv += ov; Sw += ow; }
        }

        // carry into this thread's head run (exact under sortedness)
        float cv = 0.f, cw = 0.f;
        {
            const float pv = __shfl_up(Sv, 1);
            const float pw = __shfl_up(Sw, 1);
            const int   pk = __shfl_up(tail_t, 1);
            if (lane > 0 && pk == head_t) { cv = pv; cw = pw; }
        }

        // route a closed run: strip-first/last runs -> side slots (unique
        // writer each, see analysis); interior runs -> sole contributor,
        // PLAIN STORE (no atomics).
        auto route = [&](int tt, float sv, float sw) {
            if (tt == SENT) return;
            if (tt == sfirst)      { tF[sid] = tt; vF[sid] = sv; wF[sid] = sw; }
            else if (tt == slast)  { tL[sid] = tt; vL[sid] = sv; wL[sid] = sw; }
            else                   { S[tt] = sv;   E[tt] = sw; }
        };

        // per-thread sequential run pass
        int   cur_t = head_t;
        float cur_v = cv, cur_w = cw;
        #pragma unroll
        for (int j = 0; j < VPT; ++j) {
            if (t[j] != cur_t) {
                route(cur_t, cur_v, cur_w);
                cur_t = t[j]; cur_v = 0.f; cur_w = 0.f;
            }
            cur_v += ve[j]; cur_w += w[j];
        }

        // epilogue: lanes<63 flush tail if the run doesn't continue; lane 63
        // owns the strip's side slots (always initializes both).
        const int nh = __shfl_down(head_t, 1);
        if (lane < 63) {
            if (nh != tail_t) route(cur_t, cur_v, cur_w);
        } else {
            if (sfirst == slast) {           // single-run strip (or all-invalid)
                tF[sid] = cur_t; vF[sid] = cur_v; wF[sid] = cur_w;
                tL[sid] = SENT;
            } else {                         // trailing run -> last slot
                tL[sid] = cur_t; vL[sid] = cur_v; wL[sid] = cur_w;
            }
        }
    }

    const float tot = block_reduce_sum(accA, lds);
    if (tid == 0) Apart[blockIdx.x] = tot;
}

// K1b: combine per-strip boundary runs into S/E (few, well-spread atomics).
__global__ __launch_bounds__(256)
void k1b_fix(const int* __restrict__ tF, const float* __restrict__ vF,
             const float* __restrict__ wF,
             const int* __restrict__ tL, const float* __restrict__ vL,
             const float* __restrict__ wL,
             float* __restrict__ S, float* __restrict__ E) {
    const int i = (int)blockIdx.x * 256 + (int)threadIdx.x;
    if (i >= NS) return;
    const int a = tF[i];
    if (a != SENT) { atomAddF(&S[a], vF[i]); atomAddF(&E[a], wF[i]); }
    const int b = tL[i];
    if (b != SENT) { atomAddF(&S[b], vL[i]); atomAddF(&E[b], wL[i]); }
}

// K2: per-1024-chunk partial sums of S.
__global__ __launch_bounds__(256)
void k2_partials(const float* __restrict__ S, float* __restrict__ partials) {
    __shared__ float lds[16];
    const int base = (int)blockIdx.x * 1024;
    float v = 0.f;
    for (int j = (int)threadIdx.x; j < 1024; j += 256) v += S[base + j];
    const float tot = block_reduce_sum(v, lds);
    if (threadIdx.x == 0) partials[blockIdx.x] = tot;
}

// K3: per-chunk inclusive scan of S (+offset), dot with E via log(P) -> B.
__global__ __launch_bounds__(1024)
void k3_scan_dot(const float* __restrict__ S, const float* __restrict__ E,
                 const float* __restrict__ partials, float* __restrict__ Bacc) {
    __shared__ float lds[16];
    __shared__ float wsum[16];
    __shared__ float s_off;
    const int tid  = (int)threadIdx.x;
    const int lane = tid & 63;
    const int wid  = tid >> 6;
    const int base = (int)blockIdx.x * 1024;

    float p = (tid < (int)blockIdx.x) ? partials[tid] : 0.f;
    const float off = block_reduce_sum(p, lds);
    if (tid == 0) s_off = off;
    __syncthreads();
    const float offset = s_off;

    const float x = S[base + tid];
    float s = x;
    #pragma unroll
    for (int d = 1; d < 64; d <<= 1) {
        const float o = __shfl_up(s, d);
        if (lane >= d) s += o;
    }
    if (lane == 63) wsum[wid] = s;
    __syncthreads();
    if (wid == 0) {
        float ws = (lane < 16) ? wsum[lane] : 0.f;
        #pragma unroll
        for (int d = 1; d < 16; d <<= 1) {
            const float o = __shfl_up(ws, d);
            if (lane >= d) ws += o;
        }
        if (lane < 16) wsum[lane] = ws;
    }
    __syncthreads();
    const float incl = s + (wid > 0 ? wsum[wid - 1] : 0.f);
    const float P = offset + incl;

    const float w = E[base + tid];
    const float c = (w != 0.f) ? w * __logf(P) : 0.f;
    const float tot = block_reduce_sum(c, lds);
    if (tid == 0) atomAddF(Bacc, tot);
}

// K4: reduce Apart[NBLK1], combine with B, write loss.
__global__ __launch_bounds__(256)
void k4_final(const float* __restrict__ Apart, const float* __restrict__ B,
              float* __restrict__ out, float inv_n) {
    __shared__ float lds[16];
    float v = 0.f;
    for (int j = (int)threadIdx.x; j < NBLK1; j += 256) v += Apart[j];
    const float tot = block_reduce_sum(v, lds);
    if (threadIdx.x == 0) out[0] = -(tot - B[0]) * inv_n;
}

extern "C" void kernel_launch(void* const* d_in, const int* in_sizes, int n_in,
                              void* d_out, int out_size, void* d_ws, size_t ws_size,
                              hipStream_t stream) {
    const float* risk = (const float*)d_in[0];
    const float* ev   = (const float*)d_in[1];
    const int*   tim  = (const int*)d_in[2];
    float* out = (float*)d_out;
    const int n = in_sizes[0];

    // ws (floats): S[NPAD] E[NPAD] partials[128] Apart[NBLK1] B[2]
    //              tF[NS] vF[NS] wF[NS] tL[NS] vL[NS] wL[NS]
    float* S        = (float*)d_ws;
    float* E        = S + NPAD;
    float* partials = E + NPAD;
    float* Apart    = partials + 128;
    float* B        = Apart + NBLK1;
    int*   tF       = (int*)(B + 2);
    float* vF       = (float*)(tF + NS);
    float* wF       = vF + NS;
    int*   tL       = (int*)(wF + NS);
    float* vL       = (float*)(tL + NS);
    float* wL       = vL + NS;

    // zero only what must start at 0 (side slots are always fully written)
    hipMemsetAsync(d_ws, 0, (size_t)(2 * NPAD + 128 + NBLK1 + 2) * sizeof(float), stream);

    const int elems_per_block = NWIN * 256 * VPT;  // 8192
    const int blocks = (n + elems_per_block - 1) / elems_per_block;  // 2048

    hipLaunchKernelGGL(k1_bucket, dim3(blocks), dim3(256), 0, stream,
                       risk, ev, tim, S, E, Apart, tF, vF, wF, tL, vL, wL, n);
    hipLaunchKernelGGL(k1b_fix, dim3((NS + 255) / 256), dim3(256), 0, stream,
                       tF, vF, wF, tL, vL, wL, S, E);
    hipLaunchKernelGGL(k2_partials, dim3(NBLK_SC), dim3(256), 0, stream, S, partials);
    hipLaunchKernelGGL(k3_scan_dot, dim3(NBLK_SC), dim3(1024), 0, stream, S, E, partials, B);
    hipLaunchKernelGGL(k4_final, dim3(1), dim3(256), 0, stream, Apart, B, out, 1.0f / (float)n);
}